// Round 6
// baseline (371.828 us; speedup 1.0000x reference)
//
#include <hip/hip_runtime.h>
#include <cstddef>
#include <cstdint>

// Problem constants
static constexpr int BB   = 2;
static constexpr int SS   = 384;
static constexpr int HH   = 768;
static constexpr int NHD  = 12;
static constexpr int ROWS = BB * SS;       // 768
#define SCALE_F 0.125f                     // 1/sqrt(64)

static __device__ __forceinline__ unsigned short f2bf(float x) {
    unsigned int b = __float_as_uint(x);
    b = (b + 0x7fffu + ((b >> 16) & 1u)) >> 16;   // round-to-nearest-even
    return (unsigned short)b;
}

// ---------------------------------------------------------------------------
// 64x64-tile fp32 GEMM body with register prefetch (R2-proven):
// C[i,o] = sum_k A[i,k]*W[o,k] + bias[o] (+ add[i,o])
// ---------------------------------------------------------------------------
__device__ __forceinline__ void gemm_body(const float* __restrict__ A,
                                          const float* __restrict__ W,
                                          const float* __restrict__ bias,
                                          const float* __restrict__ addsrc,
                                          float* __restrict__ C) {
    __shared__ float aT[16][68];
    __shared__ float wT[16][68];
    const int tid = threadIdx.x;
    const int i0 = blockIdx.y * 64, o0 = blockIdx.x * 64;
    const int tr = (tid >> 4) << 2;     // 0..60
    const int tc = (tid & 15) << 2;     // 0..60
    const int lr = tid >> 2;            // 0..63
    const int lk = (tid & 3) << 2;      // 0,4,8,12

    float4 av = *(const float4*)&A[(size_t)(i0 + lr) * HH + lk];
    float4 wv = *(const float4*)&W[(size_t)(o0 + lr) * HH + lk];
    float acc[4][4] = {};
    for (int k0 = 0; k0 < HH; k0 += 16) {
        __syncthreads();
        aT[lk + 0][lr] = av.x; aT[lk + 1][lr] = av.y; aT[lk + 2][lr] = av.z; aT[lk + 3][lr] = av.w;
        wT[lk + 0][lr] = wv.x; wT[lk + 1][lr] = wv.y; wT[lk + 2][lr] = wv.z; wT[lk + 3][lr] = wv.w;
        __syncthreads();
        if (k0 + 16 < HH) {   // prefetch next K-chunk while computing this one
            av = *(const float4*)&A[(size_t)(i0 + lr) * HH + k0 + 16 + lk];
            wv = *(const float4*)&W[(size_t)(o0 + lr) * HH + k0 + 16 + lk];
        }
#pragma unroll
        for (int kk = 0; kk < 16; kk++) {
            const float4 a4 = *(const float4*)&aT[kk][tr];
            const float4 w4 = *(const float4*)&wT[kk][tc];
            const float ab[4] = {a4.x, a4.y, a4.z, a4.w};
            const float wb[4] = {w4.x, w4.y, w4.z, w4.w};
#pragma unroll
            for (int r = 0; r < 4; r++)
#pragma unroll
                for (int c = 0; c < 4; c++)
                    acc[r][c] = fmaf(ab[r], wb[c], acc[r][c]);
        }
    }
#pragma unroll
    for (int r = 0; r < 4; r++) {
        const int orow = i0 + tr + r;
#pragma unroll
        for (int c = 0; c < 4; c++) {
            float v = acc[r][c] + bias[o0 + tc + c];
            if (addsrc) v += addsrc[(size_t)orow * HH + o0 + tc + c];
            C[(size_t)orow * HH + o0 + tc + c] = v;
        }
    }
}

__global__ __launch_bounds__(256) void k_gemm_qkv(const float* __restrict__ A,
                                                  const float* __restrict__ Wq, const float* __restrict__ bq,
                                                  const float* __restrict__ Wk, const float* __restrict__ bk,
                                                  const float* __restrict__ Wv, const float* __restrict__ bv,
                                                  float* __restrict__ qo, float* __restrict__ ko,
                                                  float* __restrict__ vo) {
    const int z = blockIdx.z;
    const float* W = (z == 0) ? Wq : (z == 1) ? Wk : Wv;
    const float* bias = (z == 0) ? bq : (z == 1) ? bk : bv;
    float* C = (z == 0) ? qo : (z == 1) ? ko : vo;
    gemm_body(A, W, bias, nullptr, C);
}

__global__ __launch_bounds__(256) void k_gemm_out(const float* __restrict__ A,
                                                  const float* __restrict__ W,
                                                  const float* __restrict__ bias,
                                                  const float* __restrict__ addsrc,
                                                  float* __restrict__ C) {
    gemm_body(A, W, bias, addsrc, C);
}

// ---------------------------------------------------------------------------
// U[row, h, e] = sum_d (q[row, h*64+d] + v[h,d]) * Wr[h*64+d, e]   (bf16 out)
// grid: (etile 12, rowtile 12, h 12), block 256
// ---------------------------------------------------------------------------
__global__ __launch_bounds__(256) void k_uproj(const float* __restrict__ q,
                                               const float* __restrict__ Wr,
                                               const float* __restrict__ vhead,
                                               unsigned short* __restrict__ U) {
    const int h = blockIdx.z;
    const int e0 = blockIdx.x * 64, r0 = blockIdx.y * 64;
    __shared__ float qT[64][68];   // qT[d][r]
    __shared__ float wE[64][68];   // wE[d][e]
    const int tid = threadIdx.x;
    const int lr = tid >> 2;            // 0..63
    const int bc = (tid & 3) * 16;      // 0,16,32,48
#pragma unroll
    for (int m = 0; m < 4; m++) {
        const int col = bc + m * 4;
        const float4 qv = *(const float4*)&q[(size_t)(r0 + lr) * HH + h * 64 + col];
        const float4 vv = *(const float4*)&vhead[h * 64 + col];
        qT[col + 0][lr] = qv.x + vv.x;
        qT[col + 1][lr] = qv.y + vv.y;
        qT[col + 2][lr] = qv.z + vv.z;
        qT[col + 3][lr] = qv.w + vv.w;
        const float4 wv = *(const float4*)&Wr[(size_t)(h * 64 + lr) * HH + e0 + col];
        *(float4*)&wE[lr][col] = wv;
    }
    __syncthreads();
    const int tr = (tid >> 4) << 2;
    const int tc = (tid & 15) << 2;
    float acc[4][4] = {};
#pragma unroll 8
    for (int d = 0; d < 64; d++) {
        const float4 a4 = *(const float4*)&qT[d][tr];
        const float4 b4 = *(const float4*)&wE[d][tc];
        const float ab[4] = {a4.x, a4.y, a4.z, a4.w};
        const float bb[4] = {b4.x, b4.y, b4.z, b4.w};
#pragma unroll
        for (int r = 0; r < 4; r++)
#pragma unroll
            for (int c = 0; c < 4; c++)
                acc[r][c] = fmaf(ab[r], bb[c], acc[r][c]);
    }
#pragma unroll
    for (int r = 0; r < 4; r++) {
        ushort4 o;
        o.x = f2bf(acc[r][0]); o.y = f2bf(acc[r][1]);
        o.z = f2bf(acc[r][2]); o.w = f2bf(acc[r][3]);
        *(ushort4*)&U[(size_t)(r0 + tr + r) * (NHD * HH) + (size_t)h * HH + e0 + tc] = o;
    }
}

// ---------------------------------------------------------------------------
// Fused attention core: one block per (b,i), 256 threads (4 waves).
// Phases: stage(U,qu,ext) + cb | AC (qu.k into LDS sc) | BD (stream rpe, += )
// | softmax (scale+mask, P -> sc) | PV (sc x val -> ctx global).
// LDS = 18 (Ul bf16) + 18.4 (sc) + 3 (qu) + 1.5 (ext) + cbl = 41.9 KB ->
// 3 blocks/CU, 768 blocks all co-resident (single round).
// AC/PV compute (~5K FMA/thread) hides under the 906 MB rpe HBM stream;
// k[b]/val[b] (1.18 MB each) are L2/L3-resident re-reads, not HBM.
// ---------------------------------------------------------------------------
__global__ __launch_bounds__(256) void k_bd(const float* __restrict__ rpe,
                                            const unsigned short* __restrict__ U,
                                            const float* __restrict__ q,
                                            const float* __restrict__ kk,
                                            const float* __restrict__ val,
                                            const float* __restrict__ uvec,
                                            const float* __restrict__ vvec,
                                            const float* __restrict__ br,
                                            const int* __restrict__ mask,
                                            float* __restrict__ ctx) {
    const int i = blockIdx.x;          // 0..383
    const int b = blockIdx.y;          // 0..1
    const int row = b * SS + i;
    const int tid = threadIdx.x;
    const int wave = tid >> 6;         // 0..3
    const int lane = tid & 63;

    __shared__ unsigned short Ul[NHD * HH];   // 18 KB (bf16)
    __shared__ float sc[NHD][392];            // 18.4 KB (scores -> P)
    __shared__ float qu[HH];                  // 3 KB (q + u)
    __shared__ float extl[SS];                // 1.5 KB
    __shared__ float cbl[NHD];

    // ---- stage U row (bf16), qu = q+u, mask ext; cb via shuffle ----
    {
        const uint4* Ur = (const uint4*)(U + (size_t)row * NHD * HH);
        uint4* Uld = (uint4*)Ul;
        for (int t = tid; t < NHD * HH / 8; t += 256) Uld[t] = Ur[t];
        for (int t = tid; t < HH; t += 256) qu[t] = q[(size_t)row * HH + t] + uvec[t];
        for (int t = tid; t < SS; t += 256)
            extl[t] = (1.0f - (float)mask[b * SS + t]) * (-1e18f);
        // cb[h] = sum_d (q[row,h*64+d] + v[h,d]) * br[h*64+d]; wave w -> 3 heads
#pragma unroll
        for (int hh = 0; hh < 3; hh++) {
            const int h = wave * 3 + hh;
            const int c = h * 64 + lane;
            float p = (q[(size_t)row * HH + c] + vvec[c]) * br[c];
#pragma unroll
            for (int off = 1; off < 64; off <<= 1) p += __shfl_xor(p, off);
            if (lane == 0) cbl[h] = p;
        }
    }
    __syncthreads();

    // ---- AC phase: sc[h][j] = dot64(qu_h, k[b,j,h]) + cb[h] ----
    {
        const int jsub = lane >> 3;     // 0..7
        const int dlane = lane & 7;     // 0..7
        for (int h = 0; h < NHD; h++) {
            const float4 qa = *(const float4*)&qu[h * 64 + dlane * 8];
            const float4 qb = *(const float4*)&qu[h * 64 + dlane * 8 + 4];
            const float cbh = cbl[h];
#pragma unroll 4
            for (int jg = 0; jg < 12; jg++) {
                const int j = wave * 96 + jg * 8 + jsub;
                const float* kr = &kk[(size_t)(b * SS + j) * HH + h * 64 + dlane * 8];
                const float4 k0 = *(const float4*)kr;
                const float4 k1 = *(const float4*)(kr + 4);
                float s = qa.x * k0.x;
                s = fmaf(qa.y, k0.y, s);
                s = fmaf(qa.z, k0.z, s);
                s = fmaf(qa.w, k0.w, s);
                s = fmaf(qb.x, k1.x, s);
                s = fmaf(qb.y, k1.y, s);
                s = fmaf(qb.z, k1.z, s);
                s = fmaf(qb.w, k1.w, s);
                s += __shfl_xor(s, 1);
                s += __shfl_xor(s, 2);
                s += __shfl_xor(s, 4);
                if (dlane == 0) sc[h][j] = s + cbh;
            }
        }
    }
    __syncthreads();

    // ---- BD phase: stream rpe[b,i,:,:] once, accumulate into sc ----
    {
        const int jsub = lane >> 3;      // 0..7
        const int elane = lane & 7;      // 0..7
        const float* rrow = rpe + (size_t)row * SS * HH;

        for (int g = wave; g < 12; g += 4) {
            const int jbase = g * 32 + jsub;
            const float* rp0 = rrow + (size_t)jbase * HH + (elane << 2);
            float acc[4][NHD] = {};
#pragma unroll 2
            for (int ec = 0; ec < 24; ec++) {
                const int eo = ec << 5;                 // 32 e per chunk
                const float4 t0 = *(const float4*)(rp0 + eo);
                const float4 t1 = *(const float4*)(rp0 + eo + 8 * HH);
                const float4 t2 = *(const float4*)(rp0 + eo + 16 * HH);
                const float4 t3 = *(const float4*)(rp0 + eo + 24 * HH);
                const float rb[4][4] = {{t0.x, t0.y, t0.z, t0.w},
                                        {t1.x, t1.y, t1.z, t1.w},
                                        {t2.x, t2.y, t2.z, t2.w},
                                        {t3.x, t3.y, t3.z, t3.w}};
                const int uo = eo + (elane << 2);       // ushort index, 8B aligned
#pragma unroll
                for (int h = 0; h < NHD; h++) {
                    const uint2 w2 = *(const uint2*)&Ul[h * HH + uo];
                    float ub[4];
                    ub[0] = __uint_as_float(w2.x << 16);
                    ub[1] = __uint_as_float(w2.x & 0xffff0000u);
                    ub[2] = __uint_as_float(w2.y << 16);
                    ub[3] = __uint_as_float(w2.y & 0xffff0000u);
#pragma unroll
                    for (int rr = 0; rr < 4; rr++)
#pragma unroll
                        for (int c = 0; c < 4; c++)
                            acc[rr][h] = fmaf(rb[rr][c], ub[c], acc[rr][h]);
                }
            }
#pragma unroll
            for (int rr = 0; rr < 4; rr++)
#pragma unroll
                for (int h = 0; h < NHD; h++) {
                    float a = acc[rr][h];
                    a += __shfl_xor(a, 1);
                    a += __shfl_xor(a, 2);
                    a += __shfl_xor(a, 4);
                    acc[rr][h] = a;
                }
            if (elane == 0) {
#pragma unroll
                for (int rr = 0; rr < 4; rr++) {
                    const int j = jbase + (rr << 3);
#pragma unroll
                    for (int h = 0; h < NHD; h++)
                        sc[h][j] += acc[rr][h];
                }
            }
        }
    }
    __syncthreads();

    // ---- fused softmax (scale + mask), P written back into sc ----
    {
        for (int h = wave; h < NHD; h += 4) {
            float vbuf[6];
            float m = -1e30f;
#pragma unroll
            for (int t2 = 0; t2 < 6; t2++) {
                vbuf[t2] = sc[h][lane + t2 * 64] * SCALE_F + extl[lane + t2 * 64];
                m = fmaxf(m, vbuf[t2]);
            }
#pragma unroll
            for (int off = 1; off < 64; off <<= 1) m = fmaxf(m, __shfl_xor(m, off));
            float ssum = 0.f;
#pragma unroll
            for (int t2 = 0; t2 < 6; t2++) {
                const float e = __expf(vbuf[t2] - m);
                vbuf[t2] = e;
                ssum += e;
            }
#pragma unroll
            for (int off = 1; off < 64; off <<= 1) ssum += __shfl_xor(ssum, off);
            const float inv = 1.0f / ssum;
#pragma unroll
            for (int t2 = 0; t2 < 6; t2++)
                sc[h][lane + t2 * 64] = vbuf[t2] * inv;
        }
    }
    __syncthreads();

    // ---- PV phase: ctx[row, h*64+d] = sum_j P[h,j] * val[b,j,h*64+d] ----
    {
        const int j4 = lane >> 4;    // 0..3
        const int d4 = lane & 15;    // 0..15
#pragma unroll
        for (int hh = 0; hh < 3; hh++) {
            const int h = wave * 3 + hh;
            float ax = 0.f, ay = 0.f, az = 0.f, aw = 0.f;
#pragma unroll 4
            for (int jg = 0; jg < 96; jg++) {
                const int j = (jg << 2) + j4;
                const float p = sc[h][j];
                const float4 v4 = *(const float4*)&val[(size_t)(b * SS + j) * HH + h * 64 + (d4 << 2)];
                ax = fmaf(p, v4.x, ax);
                ay = fmaf(p, v4.y, ay);
                az = fmaf(p, v4.z, az);
                aw = fmaf(p, v4.w, aw);
            }
            ax += __shfl_xor(ax, 16); ay += __shfl_xor(ay, 16);
            az += __shfl_xor(az, 16); aw += __shfl_xor(aw, 16);
            ax += __shfl_xor(ax, 32); ay += __shfl_xor(ay, 32);
            az += __shfl_xor(az, 32); aw += __shfl_xor(aw, 32);
            if (j4 == 0) {
                float4 o; o.x = ax; o.y = ay; o.z = az; o.w = aw;
                *(float4*)&ctx[(size_t)row * HH + h * 64 + (d4 << 2)] = o;
            }
        }
    }
}

// ---------------------------------------------------------------------------
// LayerNorm over last dim (768) per row
// ---------------------------------------------------------------------------
__global__ __launch_bounds__(256) void k_ln(const float* __restrict__ x,
                                            const float* __restrict__ g,
                                            const float* __restrict__ bta,
                                            float* __restrict__ o) {
    const int row = blockIdx.x;
    const int tid = threadIdx.x;
    const float* xr = x + (size_t)row * HH;
    __shared__ float red[4];
    const float v0 = xr[tid], v1 = xr[tid + 256], v2 = xr[tid + 512];
    float s = v0 + v1 + v2;
#pragma unroll
    for (int off = 1; off < 64; off <<= 1) s += __shfl_xor(s, off);
    if ((tid & 63) == 0) red[tid >> 6] = s;
    __syncthreads();
    const float mean = (red[0] + red[1] + red[2] + red[3]) * (1.0f / 768.0f);
    const float d0 = v0 - mean, d1 = v1 - mean, d2 = v2 - mean;
    float sq = d0 * d0 + d1 * d1 + d2 * d2;
#pragma unroll
    for (int off = 1; off < 64; off <<= 1) sq += __shfl_xor(sq, off);
    __syncthreads();
    if ((tid & 63) == 0) red[tid >> 6] = sq;
    __syncthreads();
    const float var = (red[0] + red[1] + red[2] + red[3]) * (1.0f / 768.0f);
    const float inv = rsqrtf(var + 1e-6f);
    o[(size_t)row * HH + tid]       = d0 * inv * g[tid]       + bta[tid];
    o[(size_t)row * HH + tid + 256] = d1 * inv * g[tid + 256] + bta[tid + 256];
    o[(size_t)row * HH + tid + 512] = d2 * inv * g[tid + 512] + bta[tid + 512];
}

// ---------------------------------------------------------------------------
extern "C" void kernel_launch(void* const* d_in, const int* in_sizes, int n_in,
                              void* d_out, int out_size, void* d_ws, size_t ws_size,
                              hipStream_t stream) {
    (void)in_sizes; (void)n_in; (void)out_size; (void)ws_size;
    const float* hs   = (const float*)d_in[0];
    const int*   mask = (const int*)d_in[1];
    const float* rpe  = (const float*)d_in[2];
    const float* Wq = (const float*)d_in[3];  const float* bq = (const float*)d_in[4];
    const float* Wk = (const float*)d_in[5];  const float* bk = (const float*)d_in[6];
    const float* Wv = (const float*)d_in[7];  const float* bv = (const float*)d_in[8];
    const float* Wr = (const float*)d_in[9];  const float* br = (const float*)d_in[10];
    const float* u  = (const float*)d_in[11]; const float* v  = (const float*)d_in[12];
    const float* Wf = (const float*)d_in[13]; const float* bf = (const float*)d_in[14];
    const float* lng = (const float*)d_in[15]; const float* lnb = (const float*)d_in[16];
    float* out = (float*)d_out;

    float* wsf     = (float*)d_ws;
    float* q_ws    = wsf;                              // 589824
    float* k_ws    = q_ws   + (size_t)ROWS * HH;
    float* v_ws    = k_ws   + (size_t)ROWS * HH;
    float* ctx_ws  = v_ws   + (size_t)ROWS * HH;
    float* lnin_ws = ctx_ws + (size_t)ROWS * HH;
    unsigned short* U_ws = (unsigned short*)(lnin_ws + (size_t)ROWS * HH); // bf16 U

    k_gemm_qkv<<<dim3(12, 12, 3), 256, 0, stream>>>(hs, Wq, bq, Wk, bk, Wv, bv,
                                                    q_ws, k_ws, v_ws);
    k_uproj<<<dim3(12, 12, 12), 256, 0, stream>>>(q_ws, Wr, v, U_ws);
    k_bd<<<dim3(SS, BB), 256, 0, stream>>>(rpe, U_ws, q_ws, k_ws, v_ws,
                                           u, v, br, mask, ctx_ws);
    k_gemm_out<<<dim3(12, 12), 256, 0, stream>>>(ctx_ws, Wf, bf, hs, lnin_ws);
    k_ln<<<dim3(768), 256, 0, stream>>>(lnin_ws, lng, lnb, out);
}

// Round 7
// 283.457 us; speedup vs baseline: 1.3118x; 1.3118x over previous
//
#include <hip/hip_runtime.h>
#include <cstddef>
#include <cstdint>

// Problem constants
static constexpr int BB   = 2;
static constexpr int SS   = 384;
static constexpr int HH   = 768;
static constexpr int NHD  = 12;
static constexpr int ROWS = BB * SS;       // 768
#define SCALE_F 0.125f                     // 1/sqrt(64)

typedef __attribute__((ext_vector_type(8))) short short8;
typedef __attribute__((ext_vector_type(4))) float f32x4;

static __device__ __forceinline__ unsigned short f2bf(float x) {
    unsigned int b = __float_as_uint(x);
    b = (b + 0x7fffu + ((b >> 16) & 1u)) >> 16;   // round-to-nearest-even
    return (unsigned short)b;
}

// ---------------------------------------------------------------------------
// fp32 -> bf16 converter: 5 equal-size arrays (hs, Wq, Wk, Wv, Wf), 589824 each
// grid (576, 5), block 256; one float4 -> ushort4 per thread
// ---------------------------------------------------------------------------
__global__ __launch_bounds__(256) void k_tobf(const float* __restrict__ s0,
                                              const float* __restrict__ s1,
                                              const float* __restrict__ s2,
                                              const float* __restrict__ s3,
                                              const float* __restrict__ s4,
                                              unsigned short* __restrict__ d0,
                                              unsigned short* __restrict__ d1,
                                              unsigned short* __restrict__ d2,
                                              unsigned short* __restrict__ d3,
                                              unsigned short* __restrict__ d4) {
    const int z = blockIdx.y;
    const float* s = (z == 0) ? s0 : (z == 1) ? s1 : (z == 2) ? s2 : (z == 3) ? s3 : s4;
    unsigned short* d = (z == 0) ? d0 : (z == 1) ? d1 : (z == 2) ? d2 : (z == 3) ? d3 : d4;
    const int t = blockIdx.x * 256 + threadIdx.x;      // < 147456
    const float4 v = *(const float4*)&s[(size_t)t * 4];
    ushort4 o;
    o.x = f2bf(v.x); o.y = f2bf(v.y); o.z = f2bf(v.z); o.w = f2bf(v.w);
    *(ushort4*)&d[(size_t)t * 4] = o;
}

// ---------------------------------------------------------------------------
// bf16 MFMA GEMM body (no LDS): C[i,o] = sum_k A[i,k]*W[o,k] + bias[o] (+add)
// A, W row-major [768][768] bf16. grid (12,12[,z]), block 256 (4 waves, 2x2
// of 32x32 per wave = 2x2 MFMA 16x16x32 tiles). Fragments straight from
// global (K-contiguous 16B/lane); weights/activations are L2-resident.
// Verified layout (m89/m91): A row=lane&15,k=(lane>>4)*8+j ; D col=lane&15,
// row=(lane>>4)*4+r.
// ---------------------------------------------------------------------------
template<bool ADD>
__device__ __forceinline__ void mfma_gemm_body(const unsigned short* __restrict__ A,
                                               const unsigned short* __restrict__ W,
                                               const float* __restrict__ bias,
                                               const float* __restrict__ addsrc,
                                               float* __restrict__ C) {
    const int tid = threadIdx.x;
    const int wid = tid >> 6, lane = tid & 63;
    const int i0 = blockIdx.y * 64, o0 = blockIdx.x * 64;
    const int wr = (wid >> 1) * 32, wc = (wid & 1) * 32;
    const int lrow = lane & 15;
    const int kgrp = (lane >> 4) * 8;

    const unsigned short* Ar0 = A + (size_t)(i0 + wr + lrow) * HH + kgrp;
    const unsigned short* Ar1 = Ar0 + 16 * HH;
    const unsigned short* Wr0 = W + (size_t)(o0 + wc + lrow) * HH + kgrp;
    const unsigned short* Wr1 = Wr0 + 16 * HH;

    f32x4 acc00 = {0.f, 0.f, 0.f, 0.f}, acc01 = {0.f, 0.f, 0.f, 0.f};
    f32x4 acc10 = {0.f, 0.f, 0.f, 0.f}, acc11 = {0.f, 0.f, 0.f, 0.f};
#pragma unroll 4
    for (int k0 = 0; k0 < HH; k0 += 32) {
        const short8 a0 = *(const short8*)(Ar0 + k0);
        const short8 a1 = *(const short8*)(Ar1 + k0);
        const short8 b0 = *(const short8*)(Wr0 + k0);
        const short8 b1 = *(const short8*)(Wr1 + k0);
        acc00 = __builtin_amdgcn_mfma_f32_16x16x32_bf16(a0, b0, acc00, 0, 0, 0);
        acc01 = __builtin_amdgcn_mfma_f32_16x16x32_bf16(a0, b1, acc01, 0, 0, 0);
        acc10 = __builtin_amdgcn_mfma_f32_16x16x32_bf16(a1, b0, acc10, 0, 0, 0);
        acc11 = __builtin_amdgcn_mfma_f32_16x16x32_bf16(a1, b1, acc11, 0, 0, 0);
    }

    const int rbase = (lane >> 4) * 4;
#pragma unroll
    for (int tr = 0; tr < 2; tr++) {
#pragma unroll
        for (int tc = 0; tc < 2; tc++) {
            const f32x4 a = (tr == 0) ? ((tc == 0) ? acc00 : acc01)
                                      : ((tc == 0) ? acc10 : acc11);
            const int col = o0 + wc + tc * 16 + lrow;
            const float bv = bias[col];
#pragma unroll
            for (int r = 0; r < 4; r++) {
                const int row = i0 + wr + tr * 16 + rbase + r;
                float v = a[r] + bv;
                if (ADD) v += addsrc[(size_t)row * HH + col];
                C[(size_t)row * HH + col] = v;
            }
        }
    }
}

__global__ __launch_bounds__(256) void k_gemm_qkv(const unsigned short* __restrict__ A,
                                                  const unsigned short* __restrict__ Wq, const float* __restrict__ bq,
                                                  const unsigned short* __restrict__ Wk, const float* __restrict__ bk,
                                                  const unsigned short* __restrict__ Wv, const float* __restrict__ bv,
                                                  float* __restrict__ qo, float* __restrict__ ko,
                                                  float* __restrict__ vo) {
    const int z = blockIdx.z;
    const unsigned short* W = (z == 0) ? Wq : (z == 1) ? Wk : Wv;
    const float* bias = (z == 0) ? bq : (z == 1) ? bk : bv;
    float* C = (z == 0) ? qo : (z == 1) ? ko : vo;
    mfma_gemm_body<false>(A, W, bias, nullptr, C);
}

__global__ __launch_bounds__(256) void k_gemm_out(const unsigned short* __restrict__ A,
                                                  const unsigned short* __restrict__ W,
                                                  const float* __restrict__ bias,
                                                  const float* __restrict__ addsrc,
                                                  float* __restrict__ C) {
    mfma_gemm_body<true>(A, W, bias, addsrc, C);
}

// ---------------------------------------------------------------------------
// U[row, h, e] = sum_d (q[row, h*64+d] + v[h,d]) * Wr[h*64+d, e]   (bf16 out)
// grid: (etile 12, rowtile 12, h 12), block 256.  e0==0 blocks also emit
// cb[row,h] = sum_d (q+v).br from the already-staged qT tile.
// ---------------------------------------------------------------------------
__global__ __launch_bounds__(256) void k_uproj(const float* __restrict__ q,
                                               const float* __restrict__ Wr,
                                               const float* __restrict__ vhead,
                                               const float* __restrict__ br,
                                               unsigned short* __restrict__ U,
                                               float* __restrict__ cb) {
    const int h = blockIdx.z;
    const int e0 = blockIdx.x * 64, r0 = blockIdx.y * 64;
    __shared__ float qT[64][68];   // qT[d][r]
    __shared__ float wE[64][68];   // wE[d][e]
    const int tid = threadIdx.x;
    const int lr = tid >> 2;            // 0..63
    const int bc = (tid & 3) * 16;      // 0,16,32,48
#pragma unroll
    for (int m = 0; m < 4; m++) {
        const int col = bc + m * 4;
        const float4 qv = *(const float4*)&q[(size_t)(r0 + lr) * HH + h * 64 + col];
        const float4 vv = *(const float4*)&vhead[h * 64 + col];
        qT[col + 0][lr] = qv.x + vv.x;
        qT[col + 1][lr] = qv.y + vv.y;
        qT[col + 2][lr] = qv.z + vv.z;
        qT[col + 3][lr] = qv.w + vv.w;
        const float4 wv = *(const float4*)&Wr[(size_t)(h * 64 + lr) * HH + e0 + col];
        *(float4*)&wE[lr][col] = wv;
    }
    __syncthreads();
    const int tr = (tid >> 4) << 2;
    const int tc = (tid & 15) << 2;
    float acc[4][4] = {};
#pragma unroll 8
    for (int d = 0; d < 64; d++) {
        const float4 a4 = *(const float4*)&qT[d][tr];
        const float4 b4 = *(const float4*)&wE[d][tc];
        const float ab[4] = {a4.x, a4.y, a4.z, a4.w};
        const float bb[4] = {b4.x, b4.y, b4.z, b4.w};
#pragma unroll
        for (int r = 0; r < 4; r++)
#pragma unroll
            for (int c = 0; c < 4; c++)
                acc[r][c] = fmaf(ab[r], bb[c], acc[r][c]);
    }
#pragma unroll
    for (int r = 0; r < 4; r++) {
        ushort4 o;
        o.x = f2bf(acc[r][0]); o.y = f2bf(acc[r][1]);
        o.z = f2bf(acc[r][2]); o.w = f2bf(acc[r][3]);
        *(ushort4*)&U[(size_t)(r0 + tr + r) * (NHD * HH) + (size_t)h * HH + e0 + tc] = o;
    }
    // cb fold: only e0==0 blocks (qT untouched since barrier; conflict-free reads)
    if (e0 == 0 && tid < 64) {
        float s = 0.f;
        for (int d = 0; d < 64; d++)
            s = fmaf(qT[d][tid], br[h * 64 + d], s);
        cb[(r0 + tid) * NHD + h] = s;
    }
}

// ---------------------------------------------------------------------------
// AC scores GEMM: sc[b,i,h,j] = sum_d (q[b,i,hd]+u[h,d]) * k[b,j,hd] + cb[b,i,h]
// grid: (jtile 6, itile 6, b*NH 24), block 256
// ---------------------------------------------------------------------------
__global__ __launch_bounds__(256) void k_ac(const float* __restrict__ q,
                                            const float* __restrict__ kk,
                                            const float* __restrict__ uvec,
                                            const float* __restrict__ cb,
                                            float* __restrict__ sc) {
    const int bh = blockIdx.z;
    const int b = bh / NHD, h = bh - b * NHD;
    const int i0 = blockIdx.y * 64, j0 = blockIdx.x * 64;
    __shared__ float qT[64][68];   // qT[d][i]
    __shared__ float kT[64][68];   // kT[d][j]
    const int tid = threadIdx.x;
    const int lr = tid >> 2;
    const int bc = (tid & 3) * 16;
#pragma unroll
    for (int m = 0; m < 4; m++) {
        const int col = bc + m * 4;
        const float4 qv = *(const float4*)&q[(size_t)(b * SS + i0 + lr) * HH + h * 64 + col];
        const float4 uv = *(const float4*)&uvec[h * 64 + col];
        qT[col + 0][lr] = qv.x + uv.x;
        qT[col + 1][lr] = qv.y + uv.y;
        qT[col + 2][lr] = qv.z + uv.z;
        qT[col + 3][lr] = qv.w + uv.w;
        const float4 kv = *(const float4*)&kk[(size_t)(b * SS + j0 + lr) * HH + h * 64 + col];
        kT[col + 0][lr] = kv.x;
        kT[col + 1][lr] = kv.y;
        kT[col + 2][lr] = kv.z;
        kT[col + 3][lr] = kv.w;
    }
    __syncthreads();
    const int tr = (tid >> 4) << 2;
    const int tc = (tid & 15) << 2;
    float acc[4][4] = {};
#pragma unroll 8
    for (int d = 0; d < 64; d++) {
        const float4 a4 = *(const float4*)&qT[d][tr];
        const float4 b4 = *(const float4*)&kT[d][tc];
        const float ab[4] = {a4.x, a4.y, a4.z, a4.w};
        const float bb[4] = {b4.x, b4.y, b4.z, b4.w};
#pragma unroll
        for (int r = 0; r < 4; r++)
#pragma unroll
            for (int c = 0; c < 4; c++)
                acc[r][c] = fmaf(ab[r], bb[c], acc[r][c]);
    }
#pragma unroll
    for (int r = 0; r < 4; r++) {
        const int i = i0 + tr + r;
        const float cbr = cb[(b * SS + i) * NHD + h];
        float4 o;
        o.x = acc[r][0] + cbr; o.y = acc[r][1] + cbr;
        o.z = acc[r][2] + cbr; o.w = acc[r][3] + cbr;
        *(float4*)&sc[((size_t)(b * SS + i) * NHD + h) * SS + j0 + tc] = o;
    }
}

// ---------------------------------------------------------------------------
// BD + softmax: one block per (b,i), 256 threads (4 waves), U in bf16 LDS.
// LDS = 18 + 18.4 + 1.5 = 37.9 KB; 768 blocks all co-resident (3/CU).
// NO min-waves hint (R4 lesson: it caps VGPR and spills).  [R5-proven]
// ---------------------------------------------------------------------------
__global__ __launch_bounds__(256) void k_bd(const float* __restrict__ rpe,
                                            const unsigned short* __restrict__ U,
                                            const int* __restrict__ mask,
                                            float* __restrict__ scP) {
    const int i = blockIdx.x;          // 0..383
    const int b = blockIdx.y;          // 0..1
    const int row = b * SS + i;
    const int tid = threadIdx.x;

    __shared__ unsigned short Ul[NHD * HH];   // 18 KB (bf16)
    __shared__ float sc[NHD][392];            // 18.4 KB
    __shared__ float extl[SS];                // 1.5 KB

    float* plane = scP + (size_t)row * NHD * SS;

    // stage U row (bf16), AC scores plane, mask
    {
        const uint4* Ur = (const uint4*)(U + (size_t)row * NHD * HH);
        uint4* Uld = (uint4*)Ul;
        for (int t = tid; t < NHD * HH / 8; t += 256) Uld[t] = Ur[t];
        for (int t = tid; t < NHD * 96; t += 256) {
            const int h = t / 96, c4 = (t - h * 96) << 2;
            *(float4*)&sc[h][c4] = *(const float4*)&plane[h * SS + c4];
        }
        for (int t = tid; t < SS; t += 256)
            extl[t] = (1.0f - (float)mask[b * SS + t]) * (-1e18f);
    }
    __syncthreads();

    const int wave = tid >> 6;       // 0..3
    const int lane = tid & 63;

    // ---- BD phase: stream rpe[b,i,:,:] once ----
    {
        const int jsub = lane >> 3;      // 0..7
        const int elane = lane & 7;      // 0..7
        const float* rrow = rpe + (size_t)row * SS * HH;

        for (int g = wave; g < 12; g += 4) {
            const int jbase = g * 32 + jsub;
            const float* rp0 = rrow + (size_t)jbase * HH + (elane << 2);
            float acc[4][NHD] = {};
#pragma unroll 2
            for (int ec = 0; ec < 24; ec++) {
                const int eo = ec << 5;                 // 32 e per chunk
                const float4 t0 = *(const float4*)(rp0 + eo);
                const float4 t1 = *(const float4*)(rp0 + eo + 8 * HH);
                const float4 t2 = *(const float4*)(rp0 + eo + 16 * HH);
                const float4 t3 = *(const float4*)(rp0 + eo + 24 * HH);
                const float rb[4][4] = {{t0.x, t0.y, t0.z, t0.w},
                                        {t1.x, t1.y, t1.z, t1.w},
                                        {t2.x, t2.y, t2.z, t2.w},
                                        {t3.x, t3.y, t3.z, t3.w}};
                const int uo = eo + (elane << 2);       // ushort index, 8B aligned
#pragma unroll
                for (int h = 0; h < NHD; h++) {
                    const uint2 w2 = *(const uint2*)&Ul[h * HH + uo];
                    float ub[4];
                    ub[0] = __uint_as_float(w2.x << 16);
                    ub[1] = __uint_as_float(w2.x & 0xffff0000u);
                    ub[2] = __uint_as_float(w2.y << 16);
                    ub[3] = __uint_as_float(w2.y & 0xffff0000u);
#pragma unroll
                    for (int rr = 0; rr < 4; rr++)
#pragma unroll
                        for (int c = 0; c < 4; c++)
                            acc[rr][h] = fmaf(rb[rr][c], ub[c], acc[rr][h]);
                }
            }
#pragma unroll
            for (int rr = 0; rr < 4; rr++)
#pragma unroll
                for (int h = 0; h < NHD; h++) {
                    float a = acc[rr][h];
                    a += __shfl_xor(a, 1);
                    a += __shfl_xor(a, 2);
                    a += __shfl_xor(a, 4);
                    acc[rr][h] = a;
                }
            if (elane == 0) {
#pragma unroll
                for (int rr = 0; rr < 4; rr++) {
                    const int j = jbase + (rr << 3);
#pragma unroll
                    for (int h = 0; h < NHD; h++)
                        sc[h][j] += acc[rr][h];
                }
            }
        }
    }
    __syncthreads();

    // ---- fused softmax (scale + mask), write P to plane ----
    {
        for (int h = wave; h < NHD; h += 4) {
            float vbuf[6];
            float m = -1e30f;
#pragma unroll
            for (int t2 = 0; t2 < 6; t2++) {
                vbuf[t2] = sc[h][lane + t2 * 64] * SCALE_F + extl[lane + t2 * 64];
                m = fmaxf(m, vbuf[t2]);
            }
#pragma unroll
            for (int off = 1; off < 64; off <<= 1) m = fmaxf(m, __shfl_xor(m, off));
            float ssum = 0.f;
#pragma unroll
            for (int t2 = 0; t2 < 6; t2++) {
                const float e = __expf(vbuf[t2] - m);
                vbuf[t2] = e;
                ssum += e;
            }
#pragma unroll
            for (int off = 1; off < 64; off <<= 1) ssum += __shfl_xor(ssum, off);
            const float inv = 1.0f / ssum;
#pragma unroll
            for (int t2 = 0; t2 < 6; t2++)
                plane[h * SS + lane + t2 * 64] = vbuf[t2] * inv;
        }
    }
}

// ---------------------------------------------------------------------------
// PV GEMM: ctx_bf16[b,i,h*64+d] = sum_j P[b,i,h,j] * val[b,j,h*64+d]
// grid: (itile 6, b*NH 24), block 256
// ---------------------------------------------------------------------------
__global__ __launch_bounds__(256) void k_pv(const float* __restrict__ P,
                                            const float* __restrict__ val,
                                            unsigned short* __restrict__ ctxb) {
    const int bh = blockIdx.y;
    const int b = bh / NHD, h = bh - b * NHD;
    const int i0 = blockIdx.x * 64;
    __shared__ float pT[64][68];   // pT[j][i]
    __shared__ float vB[64][68];   // vB[j][d]
    const int tid = threadIdx.x;
    const int lr = tid >> 2;
    const int bc = (tid & 3) * 16;
    const int tr = (tid >> 4) << 2;
    const int tc = (tid & 15) << 2;

    float4 pv[4], vv[4];
#pragma unroll
    for (int m = 0; m < 4; m++) {
        const int col = bc + m * 4;
        pv[m] = *(const float4*)&P[((size_t)(b * SS + i0 + lr) * NHD + h) * SS + col];
        vv[m] = *(const float4*)&val[(size_t)(b * SS + lr) * HH + h * 64 + col];
    }
    float acc[4][4] = {};
    for (int jt = 0; jt < SS; jt += 64) {
        __syncthreads();
#pragma unroll
        for (int m = 0; m < 4; m++) {
            const int col = bc + m * 4;
            pT[col + 0][lr] = pv[m].x; pT[col + 1][lr] = pv[m].y;
            pT[col + 2][lr] = pv[m].z; pT[col + 3][lr] = pv[m].w;
            *(float4*)&vB[lr][col] = vv[m];
        }
        __syncthreads();
        if (jt + 64 < SS) {
#pragma unroll
            for (int m = 0; m < 4; m++) {
                const int col = bc + m * 4;
                pv[m] = *(const float4*)&P[((size_t)(b * SS + i0 + lr) * NHD + h) * SS + jt + 64 + col];
                vv[m] = *(const float4*)&val[(size_t)(b * SS + jt + 64 + lr) * HH + h * 64 + col];
            }
        }
#pragma unroll 8
        for (int jj = 0; jj < 64; jj++) {
            const float4 a4 = *(const float4*)&pT[jj][tr];
            const float4 b4 = *(const float4*)&vB[jj][tc];
            const float ab[4] = {a4.x, a4.y, a4.z, a4.w};
            const float bb[4] = {b4.x, b4.y, b4.z, b4.w};
#pragma unroll
            for (int r = 0; r < 4; r++)
#pragma unroll
                for (int c = 0; c < 4; c++)
                    acc[r][c] = fmaf(ab[r], bb[c], acc[r][c]);
        }
    }
#pragma unroll
    for (int r = 0; r < 4; r++) {
        ushort4 o;
        o.x = f2bf(acc[r][0]); o.y = f2bf(acc[r][1]);
        o.z = f2bf(acc[r][2]); o.w = f2bf(acc[r][3]);
        *(ushort4*)&ctxb[(size_t)(b * SS + i0 + tr + r) * HH + h * 64 + tc] = o;
    }
}

// ---------------------------------------------------------------------------
// LayerNorm over last dim (768) per row
// ---------------------------------------------------------------------------
__global__ __launch_bounds__(256) void k_ln(const float* __restrict__ x,
                                            const float* __restrict__ g,
                                            const float* __restrict__ bta,
                                            float* __restrict__ o) {
    const int row = blockIdx.x;
    const int tid = threadIdx.x;
    const float* xr = x + (size_t)row * HH;
    __shared__ float red[4];
    const float v0 = xr[tid], v1 = xr[tid + 256], v2 = xr[tid + 512];
    float s = v0 + v1 + v2;
#pragma unroll
    for (int off = 1; off < 64; off <<= 1) s += __shfl_xor(s, off);
    if ((tid & 63) == 0) red[tid >> 6] = s;
    __syncthreads();
    const float mean = (red[0] + red[1] + red[2] + red[3]) * (1.0f / 768.0f);
    const float d0 = v0 - mean, d1 = v1 - mean, d2 = v2 - mean;
    float sq = d0 * d0 + d1 * d1 + d2 * d2;
#pragma unroll
    for (int off = 1; off < 64; off <<= 1) sq += __shfl_xor(sq, off);
    __syncthreads();
    if ((tid & 63) == 0) red[tid >> 6] = sq;
    __syncthreads();
    const float var = (red[0] + red[1] + red[2] + red[3]) * (1.0f / 768.0f);
    const float inv = rsqrtf(var + 1e-6f);
    o[(size_t)row * HH + tid]       = d0 * inv * g[tid]       + bta[tid];
    o[(size_t)row * HH + tid + 256] = d1 * inv * g[tid + 256] + bta[tid + 256];
    o[(size_t)row * HH + tid + 512] = d2 * inv * g[tid + 512] + bta[tid + 512];
}

// ---------------------------------------------------------------------------
extern "C" void kernel_launch(void* const* d_in, const int* in_sizes, int n_in,
                              void* d_out, int out_size, void* d_ws, size_t ws_size,
                              hipStream_t stream) {
    (void)in_sizes; (void)n_in; (void)out_size; (void)ws_size;
    const float* hs   = (const float*)d_in[0];
    const int*   mask = (const int*)d_in[1];
    const float* rpe  = (const float*)d_in[2];
    const float* Wq = (const float*)d_in[3];  const float* bq = (const float*)d_in[4];
    const float* Wk = (const float*)d_in[5];  const float* bk = (const float*)d_in[6];
    const float* Wv = (const float*)d_in[7];  const float* bv = (const float*)d_in[8];
    const float* Wr = (const float*)d_in[9];  const float* br = (const float*)d_in[10];
    const float* u  = (const float*)d_in[11]; const float* v  = (const float*)d_in[12];
    const float* Wf = (const float*)d_in[13]; const float* bf = (const float*)d_in[14];
    const float* lng = (const float*)d_in[15]; const float* lnb = (const float*)d_in[16];
    float* out = (float*)d_out;

    const size_t MAT = (size_t)ROWS * HH;              // 589824
    float* wsf     = (float*)d_ws;
    float* q_ws    = wsf;                              // fp32 region
    float* k_ws    = q_ws   + MAT;
    float* v_ws    = k_ws   + MAT;
    float* lnin_ws = v_ws   + MAT;
    float* cb_ws   = lnin_ws + MAT;                    // 9216
    float* sc_ws   = cb_ws  + (size_t)ROWS * NHD;      // 3538944 (scores -> P)
    unsigned short* U_ws   = (unsigned short*)(sc_ws + (size_t)ROWS * NHD * SS);
    unsigned short* hs_b   = U_ws + (size_t)ROWS * NHD * HH;
    unsigned short* Wq_b   = hs_b + MAT;
    unsigned short* Wk_b   = Wq_b + MAT;
    unsigned short* Wv_b   = Wk_b + MAT;
    unsigned short* Wf_b   = Wv_b + MAT;
    unsigned short* ctx_b  = Wf_b + MAT;

    k_tobf<<<dim3(576, 5), 256, 0, stream>>>(hs, Wq, Wk, Wv, Wf,
                                             hs_b, Wq_b, Wk_b, Wv_b, Wf_b);
    k_gemm_qkv<<<dim3(12, 12, 3), 256, 0, stream>>>(hs_b, Wq_b, bq, Wk_b, bk, Wv_b, bv,
                                                    q_ws, k_ws, v_ws);
    k_uproj<<<dim3(12, 12, 12), 256, 0, stream>>>(q_ws, Wr, v, br, U_ws, cb_ws);
    k_ac<<<dim3(6, 6, 24), 256, 0, stream>>>(q_ws, k_ws, u, cb_ws, sc_ws);
    k_bd<<<dim3(SS, BB), 256, 0, stream>>>(rpe, U_ws, mask, sc_ws);
    k_pv<<<dim3(6, 24), 256, 0, stream>>>(sc_ws, v_ws, ctx_b);
    k_gemm_out<<<dim3(12, 12), 256, 0, stream>>>(ctx_b, Wf_b, bf, hs, lnin_ws);
    k_ln<<<dim3(768), 256, 0, stream>>>(lnin_ws, lng, lnb, out);
}

// Round 8
// 262.836 us; speedup vs baseline: 1.4147x; 1.0785x over previous
//
#include <hip/hip_runtime.h>
#include <cstddef>
#include <cstdint>

// Problem constants
static constexpr int BB   = 2;
static constexpr int SS   = 384;
static constexpr int HH   = 768;
static constexpr int NHD  = 12;
static constexpr int ROWS = BB * SS;       // 768
#define SCALE_F 0.125f                     // 1/sqrt(64)

typedef __attribute__((ext_vector_type(8))) short short8;
typedef __attribute__((ext_vector_type(4))) float f32x4;

static __device__ __forceinline__ unsigned short f2bf(float x) {
    unsigned int b = __float_as_uint(x);
    b = (b + 0x7fffu + ((b >> 16) & 1u)) >> 16;   // round-to-nearest-even
    return (unsigned short)b;
}
static __device__ __forceinline__ float bf2f(unsigned short u) {
    return __uint_as_float((unsigned int)u << 16);
}

// ---------------------------------------------------------------------------
// fp32 -> bf16 converter (z<5: hs, Wq, Wk, Wv, Wf) + Wr transpose (z==5).
// grid (576, 6), block 256.
// ---------------------------------------------------------------------------
__global__ __launch_bounds__(256) void k_tobf(const float* __restrict__ s0,
                                              const float* __restrict__ s1,
                                              const float* __restrict__ s2,
                                              const float* __restrict__ s3,
                                              const float* __restrict__ s4,
                                              const float* __restrict__ Wr,
                                              unsigned short* __restrict__ d0,
                                              unsigned short* __restrict__ d1,
                                              unsigned short* __restrict__ d2,
                                              unsigned short* __restrict__ d3,
                                              unsigned short* __restrict__ d4,
                                              unsigned short* __restrict__ WrT) {
    __shared__ float t[32][33];
    const int z = blockIdx.y;
    if (z < 5) {
        const float* s = (z == 0) ? s0 : (z == 1) ? s1 : (z == 2) ? s2 : (z == 3) ? s3 : s4;
        unsigned short* d = (z == 0) ? d0 : (z == 1) ? d1 : (z == 2) ? d2 : (z == 3) ? d3 : d4;
        const int tt = blockIdx.x * 256 + threadIdx.x;      // < 147456
        const float4 v = *(const float4*)&s[(size_t)tt * 4];
        ushort4 o;
        o.x = f2bf(v.x); o.y = f2bf(v.y); o.z = f2bf(v.z); o.w = f2bf(v.w);
        *(ushort4*)&d[(size_t)tt * 4] = o;
    } else {
        // WrT[e][c] = Wr[c][e]  (bf16), 32x32 tiles, 24x24 tiles total
        const int tile = blockIdx.x;
        const int tr_ = tile / 24, tc_ = tile % 24;
        const int r = threadIdx.x >> 3, c4 = (threadIdx.x & 7) * 4;
        const float4 v = *(const float4*)&Wr[(size_t)(tr_ * 32 + r) * HH + tc_ * 32 + c4];
        t[r][c4 + 0] = v.x; t[r][c4 + 1] = v.y; t[r][c4 + 2] = v.z; t[r][c4 + 3] = v.w;
        __syncthreads();
        ushort4 o;
        o.x = f2bf(t[c4 + 0][r]); o.y = f2bf(t[c4 + 1][r]);
        o.z = f2bf(t[c4 + 2][r]); o.w = f2bf(t[c4 + 3][r]);
        *(ushort4*)&WrT[(size_t)(tc_ * 32 + r) * HH + tr_ * 32 + c4] = o;
    }
}

// ---------------------------------------------------------------------------
// qkv MFMA GEMM (no LDS): per z, C = hs @ W.T + b, emitted as bf16 operands:
//  z==0: qu_b = bf16(q + u_flat), qv_b = bf16(q + v_flat)
//  z==1: k_b  = bf16(k)
//  z==2: vT_b = bf16(v) stored transposed per head: [(b*NHD+h)*64+d][j]
// grid (12,12,3), block 256. Verified frag layout (m89/m91, R7-proven).
// ---------------------------------------------------------------------------
__global__ __launch_bounds__(256) void k_gemm_qkv(const unsigned short* __restrict__ A,
                                                  const unsigned short* __restrict__ Wqb, const float* __restrict__ bq,
                                                  const unsigned short* __restrict__ Wkb, const float* __restrict__ bk,
                                                  const unsigned short* __restrict__ Wvb, const float* __restrict__ bv,
                                                  const float* __restrict__ uvec,
                                                  const float* __restrict__ vvec,
                                                  unsigned short* __restrict__ qu_b,
                                                  unsigned short* __restrict__ qv_b,
                                                  unsigned short* __restrict__ k_b,
                                                  unsigned short* __restrict__ vT_b) {
    const int z = blockIdx.z;
    const unsigned short* W = (z == 0) ? Wqb : (z == 1) ? Wkb : Wvb;
    const float* bias = (z == 0) ? bq : (z == 1) ? bk : bv;

    const int tid = threadIdx.x;
    const int wid = tid >> 6, lane = tid & 63;
    const int i0 = blockIdx.y * 64, o0 = blockIdx.x * 64;
    const int wr = (wid >> 1) * 32, wc = (wid & 1) * 32;
    const int lrow = lane & 15;
    const int kgrp = (lane >> 4) * 8;

    const unsigned short* Ar0 = A + (size_t)(i0 + wr + lrow) * HH + kgrp;
    const unsigned short* Ar1 = Ar0 + 16 * HH;
    const unsigned short* Wr0 = W + (size_t)(o0 + wc + lrow) * HH + kgrp;
    const unsigned short* Wr1 = Wr0 + 16 * HH;

    f32x4 acc00 = {0.f,0.f,0.f,0.f}, acc01 = {0.f,0.f,0.f,0.f};
    f32x4 acc10 = {0.f,0.f,0.f,0.f}, acc11 = {0.f,0.f,0.f,0.f};
#pragma unroll 4
    for (int k0 = 0; k0 < HH; k0 += 32) {
        const short8 a0 = *(const short8*)(Ar0 + k0);
        const short8 a1 = *(const short8*)(Ar1 + k0);
        const short8 b0 = *(const short8*)(Wr0 + k0);
        const short8 b1 = *(const short8*)(Wr1 + k0);
        acc00 = __builtin_amdgcn_mfma_f32_16x16x32_bf16(a0, b0, acc00, 0, 0, 0);
        acc01 = __builtin_amdgcn_mfma_f32_16x16x32_bf16(a0, b1, acc01, 0, 0, 0);
        acc10 = __builtin_amdgcn_mfma_f32_16x16x32_bf16(a1, b0, acc10, 0, 0, 0);
        acc11 = __builtin_amdgcn_mfma_f32_16x16x32_bf16(a1, b1, acc11, 0, 0, 0);
    }

    const int rbase = (lane >> 4) * 4;
#pragma unroll
    for (int tr = 0; tr < 2; tr++) {
#pragma unroll
        for (int tc = 0; tc < 2; tc++) {
            const f32x4 a = (tr == 0) ? ((tc == 0) ? acc00 : acc01)
                                      : ((tc == 0) ? acc10 : acc11);
            const int col = o0 + wc + tc * 16 + lrow;
            const float bvv = bias[col];
            if (z == 0) {
                const float uu = uvec[col], vv = vvec[col];
#pragma unroll
                for (int r = 0; r < 4; r++) {
                    const int row = i0 + wr + tr * 16 + rbase + r;
                    const float val = a[r] + bvv;
                    qu_b[(size_t)row * HH + col] = f2bf(val + uu);
                    qv_b[(size_t)row * HH + col] = f2bf(val + vv);
                }
            } else if (z == 1) {
#pragma unroll
                for (int r = 0; r < 4; r++) {
                    const int row = i0 + wr + tr * 16 + rbase + r;
                    k_b[(size_t)row * HH + col] = f2bf(a[r] + bvv);
                }
            } else {
                const int row0 = i0 + wr + tr * 16 + rbase;
                const int bb2 = row0 / SS;
                const int jj0 = row0 - bb2 * SS;
                const int h2 = col >> 6, d2 = col & 63;
                ushort4 o;
                o.x = f2bf(a[0] + bvv); o.y = f2bf(a[1] + bvv);
                o.z = f2bf(a[2] + bvv); o.w = f2bf(a[3] + bvv);
                *(ushort4*)&vT_b[((size_t)(bb2 * NHD + h2) * 64 + d2) * SS + jj0] = o;
            }
        }
    }
}

// cb[row,h] = sum_d (q+v)[row,h*64+d] * br[h*64+d]   (from qv_b)
__global__ void k_cb(const unsigned short* __restrict__ qv,
                     const float* __restrict__ br, float* __restrict__ cb) {
    const int t = blockIdx.x * 256 + threadIdx.x;
    if (t >= ROWS * NHD) return;
    const int row = t / NHD, h = t - row * NHD;
    float s = 0.f;
    for (int d = 0; d < 64; d++)
        s = fmaf(bf2f(qv[(size_t)row * HH + h * 64 + d]), br[h * 64 + d], s);
    cb[t] = s;
}

// ---------------------------------------------------------------------------
// uproj MFMA: U[row,h,e] = sum_d qv_b[row,hd] * WrT[e,hd]  (bf16 out)
// grid (12 etile, 12 rowtile, 12 h), block 256, K=64.
// ---------------------------------------------------------------------------
__global__ __launch_bounds__(256) void k_uproj(const unsigned short* __restrict__ qv,
                                               const unsigned short* __restrict__ WrT,
                                               unsigned short* __restrict__ U) {
    const int h = blockIdx.z;
    const int e0 = blockIdx.x * 64, r0 = blockIdx.y * 64;
    const int tid = threadIdx.x;
    const int wid = tid >> 6, lane = tid & 63;
    const int wr = (wid >> 1) * 32, wc = (wid & 1) * 32;
    const int lrow = lane & 15;
    const int kgrp = (lane >> 4) * 8;

    const unsigned short* Ar0 = qv + (size_t)(r0 + wr + lrow) * HH + h * 64 + kgrp;
    const unsigned short* Ar1 = Ar0 + 16 * HH;
    const unsigned short* Br0 = WrT + (size_t)(e0 + wc + lrow) * HH + h * 64 + kgrp;
    const unsigned short* Br1 = Br0 + 16 * HH;

    f32x4 acc00 = {0.f,0.f,0.f,0.f}, acc01 = {0.f,0.f,0.f,0.f};
    f32x4 acc10 = {0.f,0.f,0.f,0.f}, acc11 = {0.f,0.f,0.f,0.f};
#pragma unroll
    for (int k0 = 0; k0 < 64; k0 += 32) {
        const short8 a0 = *(const short8*)(Ar0 + k0);
        const short8 a1 = *(const short8*)(Ar1 + k0);
        const short8 b0 = *(const short8*)(Br0 + k0);
        const short8 b1 = *(const short8*)(Br1 + k0);
        acc00 = __builtin_amdgcn_mfma_f32_16x16x32_bf16(a0, b0, acc00, 0, 0, 0);
        acc01 = __builtin_amdgcn_mfma_f32_16x16x32_bf16(a0, b1, acc01, 0, 0, 0);
        acc10 = __builtin_amdgcn_mfma_f32_16x16x32_bf16(a1, b0, acc10, 0, 0, 0);
        acc11 = __builtin_amdgcn_mfma_f32_16x16x32_bf16(a1, b1, acc11, 0, 0, 0);
    }

    const int rbase = (lane >> 4) * 4;
#pragma unroll
    for (int tr = 0; tr < 2; tr++) {
#pragma unroll
        for (int tc = 0; tc < 2; tc++) {
            const f32x4 a = (tr == 0) ? ((tc == 0) ? acc00 : acc01)
                                      : ((tc == 0) ? acc10 : acc11);
            const int e = e0 + wc + tc * 16 + lrow;
#pragma unroll
            for (int r = 0; r < 4; r++) {
                const int row = r0 + wr + tr * 16 + rbase + r;
                U[(size_t)row * (NHD * HH) + (size_t)h * HH + e] = f2bf(a[r]);
            }
        }
    }
}

// ---------------------------------------------------------------------------
// AC MFMA: sc[b,i,h,j] = sum_d qu_b[b,i,hd] * k_b[b,j,hd] + cb[b,i,h]  (f32)
// grid (6 jtile, 6 itile, 24 bh), block 256, K=64.
// ---------------------------------------------------------------------------
__global__ __launch_bounds__(256) void k_ac(const unsigned short* __restrict__ qu,
                                            const unsigned short* __restrict__ kb,
                                            const float* __restrict__ cb,
                                            float* __restrict__ sc) {
    const int bh = blockIdx.z;
    const int b = bh / NHD, h = bh - b * NHD;
    const int i0 = blockIdx.y * 64, j0 = blockIdx.x * 64;
    const int tid = threadIdx.x;
    const int wid = tid >> 6, lane = tid & 63;
    const int wr = (wid >> 1) * 32, wc = (wid & 1) * 32;
    const int lrow = lane & 15;
    const int kgrp = (lane >> 4) * 8;

    const unsigned short* Ar0 = qu + (size_t)(b * SS + i0 + wr + lrow) * HH + h * 64 + kgrp;
    const unsigned short* Ar1 = Ar0 + 16 * HH;
    const unsigned short* Br0 = kb + (size_t)(b * SS + j0 + wc + lrow) * HH + h * 64 + kgrp;
    const unsigned short* Br1 = Br0 + 16 * HH;

    f32x4 acc00 = {0.f,0.f,0.f,0.f}, acc01 = {0.f,0.f,0.f,0.f};
    f32x4 acc10 = {0.f,0.f,0.f,0.f}, acc11 = {0.f,0.f,0.f,0.f};
#pragma unroll
    for (int k0 = 0; k0 < 64; k0 += 32) {
        const short8 a0 = *(const short8*)(Ar0 + k0);
        const short8 a1 = *(const short8*)(Ar1 + k0);
        const short8 b0 = *(const short8*)(Br0 + k0);
        const short8 b1 = *(const short8*)(Br1 + k0);
        acc00 = __builtin_amdgcn_mfma_f32_16x16x32_bf16(a0, b0, acc00, 0, 0, 0);
        acc01 = __builtin_amdgcn_mfma_f32_16x16x32_bf16(a0, b1, acc01, 0, 0, 0);
        acc10 = __builtin_amdgcn_mfma_f32_16x16x32_bf16(a1, b0, acc10, 0, 0, 0);
        acc11 = __builtin_amdgcn_mfma_f32_16x16x32_bf16(a1, b1, acc11, 0, 0, 0);
    }

    const int rbase = (lane >> 4) * 4;
#pragma unroll
    for (int tr = 0; tr < 2; tr++) {
#pragma unroll
        for (int tc = 0; tc < 2; tc++) {
            const f32x4 a = (tr == 0) ? ((tc == 0) ? acc00 : acc01)
                                      : ((tc == 0) ? acc10 : acc11);
            const int j = j0 + wc + tc * 16 + lrow;
#pragma unroll
            for (int r = 0; r < 4; r++) {
                const int i = i0 + wr + tr * 16 + rbase + r;
                const float cbr = cb[(b * SS + i) * NHD + h];
                sc[((size_t)(b * SS + i) * NHD + h) * SS + j] = a[r] + cbr;
            }
        }
    }
}

// ---------------------------------------------------------------------------
// BD + softmax: one block per (b,i), 256 threads, U in bf16 LDS.  [R5/R7-proven]
// Softmax now writes P as bf16 (PV MFMA A-operand).
// ---------------------------------------------------------------------------
__global__ __launch_bounds__(256) void k_bd(const float* __restrict__ rpe,
                                            const unsigned short* __restrict__ U,
                                            const int* __restrict__ mask,
                                            const float* __restrict__ scin,
                                            unsigned short* __restrict__ Pb) {
    const int i = blockIdx.x;          // 0..383
    const int b = blockIdx.y;          // 0..1
    const int row = b * SS + i;
    const int tid = threadIdx.x;

    __shared__ unsigned short Ul[NHD * HH];   // 18 KB (bf16)
    __shared__ float sc[NHD][392];            // 18.4 KB
    __shared__ float extl[SS];                // 1.5 KB

    const float* plane = scin + (size_t)row * NHD * SS;
    unsigned short* pplane = Pb + (size_t)row * NHD * SS;

    // stage U row (bf16), AC scores plane, mask
    {
        const uint4* Ur = (const uint4*)(U + (size_t)row * NHD * HH);
        uint4* Uld = (uint4*)Ul;
        for (int t = tid; t < NHD * HH / 8; t += 256) Uld[t] = Ur[t];
        for (int t = tid; t < NHD * 96; t += 256) {
            const int h = t / 96, c4 = (t - h * 96) << 2;
            *(float4*)&sc[h][c4] = *(const float4*)&plane[h * SS + c4];
        }
        for (int t = tid; t < SS; t += 256)
            extl[t] = (1.0f - (float)mask[b * SS + t]) * (-1e18f);
    }
    __syncthreads();

    const int wave = tid >> 6;       // 0..3
    const int lane = tid & 63;

    // ---- BD phase: stream rpe[b,i,:,:] once ----
    {
        const int jsub = lane >> 3;      // 0..7
        const int elane = lane & 7;      // 0..7
        const float* rrow = rpe + (size_t)row * SS * HH;

        for (int g = wave; g < 12; g += 4) {
            const int jbase = g * 32 + jsub;
            const float* rp0 = rrow + (size_t)jbase * HH + (elane << 2);
            float acc[4][NHD] = {};
#pragma unroll 2
            for (int ec = 0; ec < 24; ec++) {
                const int eo = ec << 5;                 // 32 e per chunk
                const float4 t0 = *(const float4*)(rp0 + eo);
                const float4 t1 = *(const float4*)(rp0 + eo + 8 * HH);
                const float4 t2 = *(const float4*)(rp0 + eo + 16 * HH);
                const float4 t3 = *(const float4*)(rp0 + eo + 24 * HH);
                const float rb[4][4] = {{t0.x, t0.y, t0.z, t0.w},
                                        {t1.x, t1.y, t1.z, t1.w},
                                        {t2.x, t2.y, t2.z, t2.w},
                                        {t3.x, t3.y, t3.z, t3.w}};
                const int uo = eo + (elane << 2);       // ushort index, 8B aligned
#pragma unroll
                for (int h = 0; h < NHD; h++) {
                    const uint2 w2 = *(const uint2*)&Ul[h * HH + uo];
                    float ub[4];
                    ub[0] = __uint_as_float(w2.x << 16);
                    ub[1] = __uint_as_float(w2.x & 0xffff0000u);
                    ub[2] = __uint_as_float(w2.y << 16);
                    ub[3] = __uint_as_float(w2.y & 0xffff0000u);
#pragma unroll
                    for (int rr = 0; rr < 4; rr++)
#pragma unroll
                        for (int c = 0; c < 4; c++)
                            acc[rr][h] = fmaf(rb[rr][c], ub[c], acc[rr][h]);
                }
            }
#pragma unroll
            for (int rr = 0; rr < 4; rr++)
#pragma unroll
                for (int h = 0; h < NHD; h++) {
                    float a = acc[rr][h];
                    a += __shfl_xor(a, 1);
                    a += __shfl_xor(a, 2);
                    a += __shfl_xor(a, 4);
                    acc[rr][h] = a;
                }
            if (elane == 0) {
#pragma unroll
                for (int rr = 0; rr < 4; rr++) {
                    const int j = jbase + (rr << 3);
#pragma unroll
                    for (int h = 0; h < NHD; h++)
                        sc[h][j] += acc[rr][h];
                }
            }
        }
    }
    __syncthreads();

    // ---- fused softmax (scale + mask), write P (bf16) ----
    {
        for (int h = wave; h < NHD; h += 4) {
            float vbuf[6];
            float m = -1e30f;
#pragma unroll
            for (int t2 = 0; t2 < 6; t2++) {
                vbuf[t2] = sc[h][lane + t2 * 64] * SCALE_F + extl[lane + t2 * 64];
                m = fmaxf(m, vbuf[t2]);
            }
#pragma unroll
            for (int off = 1; off < 64; off <<= 1) m = fmaxf(m, __shfl_xor(m, off));
            float ssum = 0.f;
#pragma unroll
            for (int t2 = 0; t2 < 6; t2++) {
                const float e = __expf(vbuf[t2] - m);
                vbuf[t2] = e;
                ssum += e;
            }
#pragma unroll
            for (int off = 1; off < 64; off <<= 1) ssum += __shfl_xor(ssum, off);
            const float inv = 1.0f / ssum;
#pragma unroll
            for (int t2 = 0; t2 < 6; t2++)
                pplane[h * SS + lane + t2 * 64] = f2bf(vbuf[t2] * inv);
        }
    }
}

// ---------------------------------------------------------------------------
// PV MFMA: ctx_b[b,i,h*64+d] = sum_j P_b[b,i,h,j] * vT_b[(b,h,d),j]  (bf16 out)
// grid (6 itile, 24 bh), block 256, K=384.
// ---------------------------------------------------------------------------
__global__ __launch_bounds__(256) void k_pv(const unsigned short* __restrict__ Pb,
                                            const unsigned short* __restrict__ vTb,
                                            unsigned short* __restrict__ ctxb) {
    const int bh = blockIdx.y;
    const int b = bh / NHD, h = bh - b * NHD;
    const int i0 = blockIdx.x * 64;
    const int tid = threadIdx.x;
    const int wid = tid >> 6, lane = tid & 63;
    const int wr = (wid >> 1) * 32, wc = (wid & 1) * 32;
    const int lrow = lane & 15;
    const int kgrp = (lane >> 4) * 8;

    const unsigned short* Ar0 = Pb + ((size_t)(b * SS + i0 + wr + lrow) * NHD + h) * SS + kgrp;
    const unsigned short* Ar1 = Ar0 + (size_t)16 * NHD * SS;
    const unsigned short* Br0 = vTb + ((size_t)(b * NHD + h) * 64 + wc + lrow) * SS + kgrp;
    const unsigned short* Br1 = Br0 + 16 * SS;

    f32x4 acc00 = {0.f,0.f,0.f,0.f}, acc01 = {0.f,0.f,0.f,0.f};
    f32x4 acc10 = {0.f,0.f,0.f,0.f}, acc11 = {0.f,0.f,0.f,0.f};
#pragma unroll 4
    for (int k0 = 0; k0 < SS; k0 += 32) {
        const short8 a0 = *(const short8*)(Ar0 + k0);
        const short8 a1 = *(const short8*)(Ar1 + k0);
        const short8 b0 = *(const short8*)(Br0 + k0);
        const short8 b1 = *(const short8*)(Br1 + k0);
        acc00 = __builtin_amdgcn_mfma_f32_16x16x32_bf16(a0, b0, acc00, 0, 0, 0);
        acc01 = __builtin_amdgcn_mfma_f32_16x16x32_bf16(a0, b1, acc01, 0, 0, 0);
        acc10 = __builtin_amdgcn_mfma_f32_16x16x32_bf16(a1, b0, acc10, 0, 0, 0);
        acc11 = __builtin_amdgcn_mfma_f32_16x16x32_bf16(a1, b1, acc11, 0, 0, 0);
    }

    const int rbase = (lane >> 4) * 4;
#pragma unroll
    for (int tr = 0; tr < 2; tr++) {
#pragma unroll
        for (int tc = 0; tc < 2; tc++) {
            const f32x4 a = (tr == 0) ? ((tc == 0) ? acc00 : acc01)
                                      : ((tc == 0) ? acc10 : acc11);
            const int d = wc + tc * 16 + lrow;
#pragma unroll
            for (int r = 0; r < 4; r++) {
                const int row = b * SS + i0 + wr + tr * 16 + rbase + r;
                ctxb[(size_t)row * HH + h * 64 + d] = f2bf(a[r]);
            }
        }
    }
}

// ---------------------------------------------------------------------------
// out-proj MFMA (R7-proven): lnin = ctx_b @ Wf_b.T + bf + hs
// ---------------------------------------------------------------------------
__global__ __launch_bounds__(256) void k_gemm_out(const unsigned short* __restrict__ A,
                                                  const unsigned short* __restrict__ W,
                                                  const float* __restrict__ bias,
                                                  const float* __restrict__ addsrc,
                                                  float* __restrict__ C) {
    const int tid = threadIdx.x;
    const int wid = tid >> 6, lane = tid & 63;
    const int i0 = blockIdx.y * 64, o0 = blockIdx.x * 64;
    const int wr = (wid >> 1) * 32, wc = (wid & 1) * 32;
    const int lrow = lane & 15;
    const int kgrp = (lane >> 4) * 8;

    const unsigned short* Ar0 = A + (size_t)(i0 + wr + lrow) * HH + kgrp;
    const unsigned short* Ar1 = Ar0 + 16 * HH;
    const unsigned short* Wr0 = W + (size_t)(o0 + wc + lrow) * HH + kgrp;
    const unsigned short* Wr1 = Wr0 + 16 * HH;

    f32x4 acc00 = {0.f,0.f,0.f,0.f}, acc01 = {0.f,0.f,0.f,0.f};
    f32x4 acc10 = {0.f,0.f,0.f,0.f}, acc11 = {0.f,0.f,0.f,0.f};
#pragma unroll 4
    for (int k0 = 0; k0 < HH; k0 += 32) {
        const short8 a0 = *(const short8*)(Ar0 + k0);
        const short8 a1 = *(const short8*)(Ar1 + k0);
        const short8 b0 = *(const short8*)(Wr0 + k0);
        const short8 b1 = *(const short8*)(Wr1 + k0);
        acc00 = __builtin_amdgcn_mfma_f32_16x16x32_bf16(a0, b0, acc00, 0, 0, 0);
        acc01 = __builtin_amdgcn_mfma_f32_16x16x32_bf16(a0, b1, acc01, 0, 0, 0);
        acc10 = __builtin_amdgcn_mfma_f32_16x16x32_bf16(a1, b0, acc10, 0, 0, 0);
        acc11 = __builtin_amdgcn_mfma_f32_16x16x32_bf16(a1, b1, acc11, 0, 0, 0);
    }

    const int rbase = (lane >> 4) * 4;
#pragma unroll
    for (int tr = 0; tr < 2; tr++) {
#pragma unroll
        for (int tc = 0; tc < 2; tc++) {
            const f32x4 a = (tr == 0) ? ((tc == 0) ? acc00 : acc01)
                                      : ((tc == 0) ? acc10 : acc11);
            const int col = o0 + wc + tc * 16 + lrow;
            const float bv = bias[col];
#pragma unroll
            for (int r = 0; r < 4; r++) {
                const int row = i0 + wr + tr * 16 + rbase + r;
                C[(size_t)row * HH + col] = a[r] + bv + addsrc[(size_t)row * HH + col];
            }
        }
    }
}

// ---------------------------------------------------------------------------
// LayerNorm over last dim (768) per row
// ---------------------------------------------------------------------------
__global__ __launch_bounds__(256) void k_ln(const float* __restrict__ x,
                                            const float* __restrict__ g,
                                            const float* __restrict__ bta,
                                            float* __restrict__ o) {
    const int row = blockIdx.x;
    const int tid = threadIdx.x;
    const float* xr = x + (size_t)row * HH;
    __shared__ float red[4];
    const float v0 = xr[tid], v1 = xr[tid + 256], v2 = xr[tid + 512];
    float s = v0 + v1 + v2;
#pragma unroll
    for (int off = 1; off < 64; off <<= 1) s += __shfl_xor(s, off);
    if ((tid & 63) == 0) red[tid >> 6] = s;
    __syncthreads();
    const float mean = (red[0] + red[1] + red[2] + red[3]) * (1.0f / 768.0f);
    const float d0 = v0 - mean, d1 = v1 - mean, d2 = v2 - mean;
    float sq = d0 * d0 + d1 * d1 + d2 * d2;
#pragma unroll
    for (int off = 1; off < 64; off <<= 1) sq += __shfl_xor(sq, off);
    __syncthreads();
    if ((tid & 63) == 0) red[tid >> 6] = sq;
    __syncthreads();
    const float var = (red[0] + red[1] + red[2] + red[3]) * (1.0f / 768.0f);
    const float inv = rsqrtf(var + 1e-6f);
    o[(size_t)row * HH + tid]       = d0 * inv * g[tid]       + bta[tid];
    o[(size_t)row * HH + tid + 256] = d1 * inv * g[tid + 256] + bta[tid + 256];
    o[(size_t)row * HH + tid + 512] = d2 * inv * g[tid + 512] + bta[tid + 512];
}

// ---------------------------------------------------------------------------
extern "C" void kernel_launch(void* const* d_in, const int* in_sizes, int n_in,
                              void* d_out, int out_size, void* d_ws, size_t ws_size,
                              hipStream_t stream) {
    (void)in_sizes; (void)n_in; (void)out_size; (void)ws_size;
    const float* hs   = (const float*)d_in[0];
    const int*   mask = (const int*)d_in[1];
    const float* rpe  = (const float*)d_in[2];
    const float* Wq = (const float*)d_in[3];  const float* bq = (const float*)d_in[4];
    const float* Wk = (const float*)d_in[5];  const float* bk = (const float*)d_in[6];
    const float* Wv = (const float*)d_in[7];  const float* bv = (const float*)d_in[8];
    const float* Wr = (const float*)d_in[9];  const float* br = (const float*)d_in[10];
    const float* u  = (const float*)d_in[11]; const float* v  = (const float*)d_in[12];
    const float* Wf = (const float*)d_in[13]; const float* bf = (const float*)d_in[14];
    const float* lng = (const float*)d_in[15]; const float* lnb = (const float*)d_in[16];
    float* out = (float*)d_out;

    const size_t MAT = (size_t)ROWS * HH;              // 589824
    float* wsf     = (float*)d_ws;
    float* lnin_ws = wsf;                              // fp32 region
    float* sc_ws   = lnin_ws + MAT;                    // ROWS*NHD*SS f32
    float* cb_ws   = sc_ws + (size_t)ROWS * NHD * SS;  // 9216
    unsigned short* U_ws  = (unsigned short*)(cb_ws + (size_t)ROWS * NHD);
    unsigned short* hs_b  = U_ws + (size_t)ROWS * NHD * HH;
    unsigned short* Wq_b  = hs_b + MAT;
    unsigned short* Wk_b  = Wq_b + MAT;
    unsigned short* Wv_b  = Wk_b + MAT;
    unsigned short* Wf_b  = Wv_b + MAT;
    unsigned short* WrT_b = Wf_b + MAT;
    unsigned short* qu_b  = WrT_b + MAT;
    unsigned short* qv_b  = qu_b + MAT;
    unsigned short* k_b   = qv_b + MAT;
    unsigned short* vT_b  = k_b + MAT;
    unsigned short* ctx_b = vT_b + MAT;
    unsigned short* P_b   = ctx_b + MAT;               // ROWS*NHD*SS bf16

    k_tobf<<<dim3(576, 6), 256, 0, stream>>>(hs, Wq, Wk, Wv, Wf, Wr,
                                             hs_b, Wq_b, Wk_b, Wv_b, Wf_b, WrT_b);
    k_gemm_qkv<<<dim3(12, 12, 3), 256, 0, stream>>>(hs_b, Wq_b, bq, Wk_b, bk, Wv_b, bv,
                                                    u, v, qu_b, qv_b, k_b, vT_b);
    k_cb<<<dim3(36), 256, 0, stream>>>(qv_b, br, cb_ws);
    k_uproj<<<dim3(12, 12, 12), 256, 0, stream>>>(qv_b, WrT_b, U_ws);
    k_ac<<<dim3(6, 6, 24), 256, 0, stream>>>(qu_b, k_b, cb_ws, sc_ws);
    k_bd<<<dim3(SS, BB), 256, 0, stream>>>(rpe, U_ws, mask, sc_ws, P_b);
    k_pv<<<dim3(6, 24), 256, 0, stream>>>(P_b, vT_b, ctx_b);
    k_gemm_out<<<dim3(12, 12), 256, 0, stream>>>(ctx_b, Wf_b, bf, hs, lnin_ws);
    k_ln<<<dim3(768), 256, 0, stream>>>(lnin_ws, lng, lnb, out);
}